// Round 2
// baseline (66.059 us; speedup 1.0000x reference)
//
#include <hip/hip_runtime.h>

// DGT forward, collapsed to a binary-tree descent on sign(pred_z[node]).
// out = softmax(W_or[:, leaf]) and std = clip(action_stds[:, leaf]) depend
// only on leaf -> precomputed per-leaf tables (1024 x 16 each) in a pre-pass.
//
// Main kernel: 8-lane groups (8 samples/wave), x held in f64 registers,
// f64 accumulate (must match the f64 numpy reference's signs), 4 independent
// accumulator chains, 3-step f64 butterfly reduce.

#define BATCH   65536
#define IN_DIM  256
#define HEIGHT  10
#define NLEAF   1024
#define OUT_DIM 16

__device__ float g_out_tab[NLEAF][OUT_DIM];
__device__ float g_std_tab[NLEAF][OUT_DIM];

__global__ __launch_bounds__(256) void dgt_prepass(
    const float* __restrict__ W_or, const float* __restrict__ a_std)
{
    const int leaf = blockIdx.x * 256 + threadIdx.x;   // 4 blocks x 256
    float z[OUT_DIM];
    float m = -3.4e38f;
    #pragma unroll
    for (int c = 0; c < OUT_DIM; ++c) {
        z[c] = W_or[c * NLEAF + leaf];                 // coalesced per c
        m = fmaxf(m, z[c]);
    }
    float s = 0.f;
    #pragma unroll
    for (int c = 0; c < OUT_DIM; ++c) { z[c] = __expf(z[c] - m); s += z[c]; }
    #pragma unroll
    for (int c = 0; c < OUT_DIM; ++c) g_out_tab[leaf][c] = z[c] / s;
    #pragma unroll
    for (int c = 0; c < OUT_DIM; ++c) {
        float v = a_std[c * NLEAF + leaf];
        g_std_tab[leaf][c] = fminf(fmaxf(v, -20.f), 2.f);
    }
}

// 256 threads = 4 waves; 8 samples per wave (8-lane groups) -> 32/block.
__global__ __launch_bounds__(256, 4) void dgt_main(
    const float* __restrict__ x,
    const float* __restrict__ W_pred,
    const float* __restrict__ b_pred,
    float* __restrict__ out)
{
    const int lane = threadIdx.x & 63;
    const int wid  = threadIdx.x >> 6;   // wave in block (0..3)
    const int g    = lane >> 3;          // sample group within wave (0..7)
    const int l    = lane & 7;           // lane within group (0..7)
    const int sample = (blockIdx.x * 4 + wid) * 8 + g;

    // x row in f64 registers: elem k*32 + l*4 + c -> xr[k*4+c].
    // Each k is a coalesced 128B segment per 8-lane group.
    double xr[32];
    const float* xrow = x + (size_t)sample * IN_DIM;
    #pragma unroll
    for (int k = 0; k < 8; ++k) {
        float4 v = *reinterpret_cast<const float4*>(xrow + k * 32 + l * 4);
        xr[k*4+0] = (double)v.x; xr[k*4+1] = (double)v.y;
        xr[k*4+2] = (double)v.z; xr[k*4+3] = (double)v.w;
    }

    // Tree descent; pred_z[node] >= 0 -> left child.
    int pos = 0, node = 0;
    #pragma unroll
    for (int lvl = 0; lvl < HEIGHT; ++lvl) {
        const float* wrow = W_pred + (size_t)node * IN_DIM;
        // 4 independent partials: dependent-add chain 8 deep, not 32.
        double a0 = 0.0, a1 = 0.0, a2 = 0.0, a3 = 0.0;
        #pragma unroll
        for (int k = 0; k < 8; ++k) {
            float4 w = *reinterpret_cast<const float4*>(wrow + k * 32 + l * 4);
            a0 += xr[k*4+0] * (double)w.x;
            a1 += xr[k*4+1] * (double)w.y;
            a2 += xr[k*4+2] * (double)w.z;
            a3 += xr[k*4+3] * (double)w.w;
        }
        double acc = (a0 + a1) + (a2 + a3);
        // 3-step butterfly across the 8-lane group; bitwise-uniform result.
        #pragma unroll
        for (int off = 4; off > 0; off >>= 1)
            acc += __shfl_xor(acc, off, 64);
        acc += (double)b_pred[node];
        pos  = 2 * pos + (acc < 0.0 ? 1 : 0);
        node = (2 << lvl) - 1 + pos;     // first node of next level + pos
    }
    const int leaf = pos;                // in [0, 1024)

    // Epilogue: pure table lookup. Lane l handles classes {2l, 2l+1};
    // per wave the stores cover 8 consecutive samples = 512B contiguous.
    float2 o  = *reinterpret_cast<const float2*>(&g_out_tab[leaf][l * 2]);
    float2 sd = *reinterpret_cast<const float2*>(&g_std_tab[leaf][l * 2]);
    *reinterpret_cast<float2*>(out + (size_t)sample * OUT_DIM + l * 2) = o;
    *reinterpret_cast<float2*>(out + (size_t)BATCH * OUT_DIM
                               + (size_t)sample * OUT_DIM + l * 2) = sd;
}

extern "C" void kernel_launch(void* const* d_in, const int* in_sizes, int n_in,
                              void* d_out, int out_size, void* d_ws, size_t ws_size,
                              hipStream_t stream) {
    const float* x      = (const float*)d_in[0];
    const float* W_pred = (const float*)d_in[1];
    const float* b_pred = (const float*)d_in[2];
    const float* W_or   = (const float*)d_in[3];
    const float* a_std  = (const float*)d_in[4];
    float* out = (float*)d_out;

    hipLaunchKernelGGL(dgt_prepass, dim3(NLEAF / 256), dim3(256), 0, stream,
                       W_or, a_std);
    hipLaunchKernelGGL(dgt_main, dim3(BATCH / 32), dim3(256), 0, stream,
                       x, W_pred, b_pred, out);
}

// Round 3
// 54.514 us; speedup vs baseline: 1.2118x; 1.2118x over previous
//
#include <hip/hip_runtime.h>

// DGT forward, collapsed to a binary-tree descent on sign(pred_z[node]).
// f32 fast path for the per-node dot + sign; rare f64 recompute when
// |z_f32| < EPS_TIE (the only region where f32 sign can disagree with the
// f64 numpy reference). Speculative dual-dot of both children overlaps the
// dot work with the butterfly-reduce latency; child rows + biases are
// prefetched one level ahead.
//
// Shapes: x [65536,256] f32, W_pred [1023,256], b_pred [1023],
//         W_or [16,1024], action_stds [16,1024].
// d_out = [out (65536x16) | std (65536x16)] f32.

#define BATCH   65536
#define IN_DIM  256
#define NLEVEL  10
#define NLEAF   1024
#define OUT_DIM 16
#define EPS_TIE 1e-4f

// 256 threads = 4 waves; 16-lane groups -> 4 samples/wave, 16/block.
__global__ __launch_bounds__(256, 4) void dgt_kernel(
    const float* __restrict__ x,
    const float* __restrict__ W_pred,
    const float* __restrict__ b_pred,
    const float* __restrict__ W_or,
    const float* __restrict__ a_std,
    float* __restrict__ out)
{
    const int lane = threadIdx.x & 63;
    const int wid  = threadIdx.x >> 6;   // wave in block (0..3)
    const int l    = lane & 15;          // lane within 16-group
    const int g    = lane >> 4;          // group (sample) within wave
    const int sample = (blockIdx.x * 4 + wid) * 4 + g;

    // x fragment: elem k*64 + l*4 + c; 256B coalesced segments per group.
    const float* xrow = x + (size_t)sample * IN_DIM;
    float4 xq[4];
    #pragma unroll
    for (int k = 0; k < 4; ++k)
        xq[k] = *reinterpret_cast<const float4*>(xrow + k * 64 + l * 4);

    // Prologue: dot of root row; prefetch rows+biases of nodes 1,2.
    float4 rl[4], rr[4];
    #pragma unroll
    for (int k = 0; k < 4; ++k) {
        rl[k] = *reinterpret_cast<const float4*>(W_pred + 1 * IN_DIM + k * 64 + l * 4);
        rr[k] = *reinterpret_cast<const float4*>(W_pred + 2 * IN_DIM + k * 64 + l * 4);
    }
    float bL = b_pred[1], bR = b_pred[2];

    float pa0 = 0.f, pa1 = 0.f, pa2 = 0.f, pa3 = 0.f;
    {
        #pragma unroll
        for (int k = 0; k < 4; ++k) {
            float4 w = *reinterpret_cast<const float4*>(W_pred + k * 64 + l * 4);
            pa0 += xq[k].x * w.x; pa1 += xq[k].y * w.y;
            pa2 += xq[k].z * w.z; pa3 += xq[k].w * w.w;
        }
    }
    float bcur = b_pred[0];

    int node = 0, pos = 0;

    #pragma unroll
    for (int lvl = 0; lvl < NLEVEL; ++lvl) {
        // (a) speculative dual-dot of both child rows (independent of sign;
        // overlaps the butterfly below). Candidates for level lvl+1.
        float qL0=0.f,qL1=0.f,qL2=0.f,qL3=0.f, qR0=0.f,qR1=0.f,qR2=0.f,qR3=0.f;
        if (lvl < NLEVEL - 1) {
            #pragma unroll
            for (int k = 0; k < 4; ++k) {
                qL0 += xq[k].x * rl[k].x; qL1 += xq[k].y * rl[k].y;
                qL2 += xq[k].z * rl[k].z; qL3 += xq[k].w * rl[k].w;
                qR0 += xq[k].x * rr[k].x; qR1 += xq[k].y * rr[k].y;
                qR2 += xq[k].z * rr[k].z; qR3 += xq[k].w * rr[k].w;
            }
        }

        // (b) butterfly-reduce current node's partials (bitwise-uniform
        // across the 16-lane group: xor pairing + commutative adds).
        float zz = (pa0 + pa1) + (pa2 + pa3);
        #pragma unroll
        for (int off = 8; off > 0; off >>= 1)
            zz += __shfl_xor(zz, off, 64);
        zz += bcur;

        // Sign; f64 recompute when too close to zero for f32 to be trusted.
        int right;
        if (__builtin_expect(fabsf(zz) >= EPS_TIE, 1)) {
            right = (zz < 0.f) ? 1 : 0;
        } else {
            // Rare (P ~ 8e-5/decision). Group-uniform branch: all 16 lanes
            // of a group enter together, so xor-shuffle partners are active.
            const float* wrow = W_pred + (size_t)node * IN_DIM;
            double A0 = 0.0, A1 = 0.0, A2 = 0.0, A3 = 0.0;
            #pragma unroll
            for (int k = 0; k < 4; ++k) {
                float4 w = *reinterpret_cast<const float4*>(wrow + k * 64 + l * 4);
                A0 += (double)xq[k].x * (double)w.x;
                A1 += (double)xq[k].y * (double)w.y;
                A2 += (double)xq[k].z * (double)w.z;
                A3 += (double)xq[k].w * (double)w.w;
            }
            double Z = (A0 + A1) + (A2 + A3);
            #pragma unroll
            for (int off = 8; off > 0; off >>= 1)
                Z += __shfl_xor(Z, off, 64);
            Z += (double)bcur;
            right = (Z < 0.0) ? 1 : 0;
        }

        pos = 2 * pos + right;
        node = 2 * node + 1 + right;

        if (lvl < NLEVEL - 1) {
            // (c) select surviving child's partials (cheap, on sign path).
            pa0 = right ? qR0 : qL0; pa1 = right ? qR1 : qL1;
            pa2 = right ? qR2 : qL2; pa3 = right ? qR3 : qL3;
            bcur = right ? bR : bL;
            // (d) prefetch grandchild rows + biases for the next level.
            if (lvl < NLEVEL - 2) {
                const float* wl = W_pred + (size_t)(2 * node + 1) * IN_DIM;
                const float* wr = W_pred + (size_t)(2 * node + 2) * IN_DIM;
                #pragma unroll
                for (int k = 0; k < 4; ++k) {
                    rl[k] = *reinterpret_cast<const float4*>(wl + k * 64 + l * 4);
                    rr[k] = *reinterpret_cast<const float4*>(wr + k * 64 + l * 4);
                }
                bL = b_pred[2 * node + 1];
                bR = b_pred[2 * node + 2];
            }
        }
    }
    const int leaf = pos;  // in [0, 1024)

    // Epilogue: softmax over 16 classes of W_or[:, leaf]; one class/lane.
    float z = W_or[l * NLEAF + leaf];
    float m = z;
    #pragma unroll
    for (int off = 8; off > 0; off >>= 1)
        m = fmaxf(m, __shfl_xor(m, off, 64));
    float e = __expf(z - m);
    float s = e;
    #pragma unroll
    for (int off = 8; off > 0; off >>= 1)
        s += __shfl_xor(s, off, 64);
    // Wave-wide store address = base*16 + lane -> contiguous 256B/wave.
    out[(size_t)sample * OUT_DIM + l] = e / s;

    float sd = a_std[l * NLEAF + leaf];
    sd = fminf(fmaxf(sd, -20.0f), 2.0f);
    out[(size_t)BATCH * OUT_DIM + (size_t)sample * OUT_DIM + l] = sd;
}

extern "C" void kernel_launch(void* const* d_in, const int* in_sizes, int n_in,
                              void* d_out, int out_size, void* d_ws, size_t ws_size,
                              hipStream_t stream) {
    const float* x      = (const float*)d_in[0];
    const float* W_pred = (const float*)d_in[1];
    const float* b_pred = (const float*)d_in[2];
    const float* W_or   = (const float*)d_in[3];
    const float* a_std  = (const float*)d_in[4];
    float* out = (float*)d_out;

    hipLaunchKernelGGL(dgt_kernel, dim3(BATCH / 16), dim3(256), 0, stream,
                       x, W_pred, b_pred, W_or, a_std, out);
}